// Round 1
// baseline (307.981 us; speedup 1.0000x reference)
//
#include <hip/hip_runtime.h>

// Hydra_56633438765296: two-head LoLa/CoLa jet network, fp32.
// B=32768 rows. Head1 (ISR): 10 jets -> 32 particles -> 160 feats -> BN -> 200 -> 10.
// top-6 selection (sorted original order) -> Head2 (DEC): 6 -> 28 -> 140 -> BN -> 200 -> 11.
// Output [B][21] = concat(out_isr, out_dec).
// BatchNorm is train-mode (batch mean / biased var) => needs global reduction:
// done as per-block partials + deterministic tree reduce (no float atomics).

#define BATCH 32768
#define NJ 10
#define FFDIM 200
#define OUTSTRIDE 21

// ---------------- features kernel: cola + lola + BN partials ----------------
// NIN input 4-vectors, NP = NIN + 22 total particles, F = NP*5 features.
template<int NIN, int NP>
__global__ __launch_bounds__(256) void feat_kernel(
    const float* __restrict__ vin,    // [B][NIN][4]
    const float* __restrict__ cola,   // [22][NIN]
    const float* __restrict__ we,     // [NP][NP]
    const float* __restrict__ wd,     // [NP][NP]
    float* __restrict__ fout,         // [B][F]
    float* __restrict__ psum,         // [4096][F]
    float* __restrict__ psq)          // [4096][F]
{
    constexpr int NC = 22;
    constexpr int F  = NP * 5;
    constexpr int RB = 8;             // rows per block
    __shared__ float s_cola[NC * NIN];
    __shared__ float s_we[NP * NP];
    __shared__ float s_wd[NP * NP];
    __shared__ float s_x[RB][NP][4];
    __shared__ float s_m2[RB][NP];
    __shared__ float s_f[RB * F];

    const int tid = threadIdx.x;
    const int blk = blockIdx.x;

    for (int k = tid; k < NC * NIN; k += 256) s_cola[k] = cola[k];
    for (int k = tid; k < NP * NP; k += 256) { s_we[k] = we[k]; s_wd[k] = wd[k]; }
    // load RB rows of input vectors (contiguous, coalesced)
    for (int k = tid; k < RB * NIN * 4; k += 256) {
        int r = k / (NIN * 4); int rem = k % (NIN * 4);
        s_x[r][rem >> 2][rem & 3] = vin[(size_t)blk * RB * NIN * 4 + k];
    }
    __syncthreads();

    const int r = tid >> 5;          // row in block (8)
    const int i = tid & 31;          // particle slot (NP <= 32)

    if (i >= NIN && i < NP) {        // learned combos
        const int c = i - NIN;
        float x0 = 0, x1 = 0, x2 = 0, x3 = 0;
        #pragma unroll
        for (int j = 0; j < NIN; j++) {
            const float w = s_cola[c * NIN + j];
            x0 += w * s_x[r][j][0]; x1 += w * s_x[r][j][1];
            x2 += w * s_x[r][j][2]; x3 += w * s_x[r][j][3];
        }
        s_x[r][i][0] = x0; s_x[r][i][1] = x1; s_x[r][i][2] = x2; s_x[r][i][3] = x3;
    }
    __syncthreads();

    float m2 = 0, pt = 0, E = 0, px = 0, py = 0, pz = 0, wesum = 0;
    if (i < NP) {
        E = s_x[r][i][0]; px = s_x[r][i][1]; py = s_x[r][i][2]; pz = s_x[r][i][3];
        m2 = E * E - px * px - py * py - pz * pz;
        pt = sqrtf(px * px + py * py);
        s_m2[r][i] = m2;
        for (int j = 0; j < NP; j++) wesum += s_we[i * NP + j] * s_x[r][j][0];
    }
    __syncthreads();
    if (i < NP) {
        float wdsum = 0;
        for (int j = 0; j < NP; j++) {
            const float g = E * s_x[r][j][0] - px * s_x[r][j][1]
                          - py * s_x[r][j][2] - pz * s_x[r][j][3];
            const float d2 = m2 + s_m2[r][j] - 2.0f * g;
            wdsum += s_wd[i * NP + j] * d2;
        }
        s_f[r * F + i * 5 + 0] = m2;
        s_f[r * F + i * 5 + 1] = pt;
        s_f[r * F + i * 5 + 2] = E;
        s_f[r * F + i * 5 + 3] = wesum;
        s_f[r * F + i * 5 + 4] = wdsum;
    }
    __syncthreads();

    for (int k = tid; k < RB * F; k += 256)
        fout[(size_t)blk * RB * F + k] = s_f[k];

    if (tid < F) {                   // per-block BN partials (deterministic)
        float s = 0, s2 = 0;
        #pragma unroll
        for (int rr = 0; rr < RB; rr++) { const float v = s_f[rr * F + tid]; s += v; s2 += v * v; }
        psum[(size_t)blk * F + tid] = s;
        psq [(size_t)blk * F + tid] = s2;
    }
}

// ---------------- BN reduce: partials -> per-feature scale/shift ----------------
template<int F>
__global__ __launch_bounds__(256) void bn_reduce(
    const float* __restrict__ psum, const float* __restrict__ psq, int nblk,
    const float* __restrict__ gamma, const float* __restrict__ beta,
    float* __restrict__ bn)          // [2*F]: scale then shift
{
    __shared__ float s1[256], s2[256];
    const int f = blockIdx.x, tid = threadIdx.x;
    float a = 0, b = 0;
    for (int bk = tid; bk < nblk; bk += 256) {
        a += psum[(size_t)bk * F + f];
        b += psq [(size_t)bk * F + f];
    }
    s1[tid] = a; s2[tid] = b; __syncthreads();
    for (int s = 128; s > 0; s >>= 1) {
        if (tid < s) { s1[tid] += s1[tid + s]; s2[tid] += s2[tid + s]; }
        __syncthreads();
    }
    if (tid == 0) {
        const float mu  = s1[0] / (float)BATCH;
        const float var = s2[0] / (float)BATCH - mu * mu;
        const float sc  = gamma[f] * rsqrtf(var + 1e-5f);
        bn[f]     = sc;
        bn[F + f] = beta[f] - mu * sc;
    }
}

// ---------------- MLP kernel: BN affine + FC1(relu) + FC2 (+ top-6 select) ----------------
template<int NF, int NOUT, bool SELECT>
__global__ __launch_bounds__(256) void mlp_kernel(
    const float* __restrict__ fin,   // [B][NF]
    const float* __restrict__ bn,    // [2*NF]
    const float* __restrict__ w1,    // [200][NF]
    const float* __restrict__ b1,    // [200]
    const float* __restrict__ w2,    // [NOUT][200]
    const float* __restrict__ b2,    // [NOUT]
    const float* __restrict__ vectors, // [B][10][4] (SELECT only)
    float* __restrict__ selout,      // [B][6][4]   (SELECT only)
    float* __restrict__ out,         // [B][21]
    int out_off)
{
    constexpr int RB = 32;           // rows per block
    constexpr int RP = 36;           // padded row stride in LDS (16B-aligned, conflict-free)
    __shared__ float s_scale[NF], s_shift[NF];
    __shared__ float FT[NF * RP];    // features transposed: [k][r]
    __shared__ float HT[FFDIM * RP]; // hidden transposed:   [n][r]
    __shared__ float s_out[RB * 16];
    __shared__ int   s_idx[RB * 6];

    const int tid = threadIdx.x;
    const int blk = blockIdx.x;

    for (int k = tid; k < NF; k += 256) { s_scale[k] = bn[k]; s_shift[k] = bn[NF + k]; }
    __syncthreads();

    // Phase A: load features (coalesced float4), apply BN affine, store transposed.
    constexpr int NF4 = NF / 4;
    for (int q = tid; q < RB * NF4; q += 256) {
        const int r = q / NF4, c4 = q % NF4, c = c4 * 4;
        const float4 v = *reinterpret_cast<const float4*>(
            fin + (size_t)(blk * RB + r) * NF + c);
        FT[(c + 0) * RP + r] = v.x * s_scale[c + 0] + s_shift[c + 0];
        FT[(c + 1) * RP + r] = v.y * s_scale[c + 1] + s_shift[c + 1];
        FT[(c + 2) * RP + r] = v.z * s_scale[c + 2] + s_shift[c + 2];
        FT[(c + 3) * RP + r] = v.w * s_scale[c + 3] + s_shift[c + 3];
    }
    __syncthreads();

    // Phase B: H[32 rows][200] = relu(W1 @ f + b1). Thread = 4 rows x 7 neurons.
    {
        const int r4 = (tid & 7) * 4;
        const int nc = tid >> 3;     // 0..31
        float acc[7][4];
        #pragma unroll
        for (int j = 0; j < 7; j++)
            #pragma unroll
            for (int rr = 0; rr < 4; rr++) acc[j][rr] = 0.0f;

        for (int kc = 0; kc < NF4; kc++) {
            const int k = kc * 4;
            const float4 f0 = *reinterpret_cast<const float4*>(&FT[(k + 0) * RP + r4]);
            const float4 f1 = *reinterpret_cast<const float4*>(&FT[(k + 1) * RP + r4]);
            const float4 f2 = *reinterpret_cast<const float4*>(&FT[(k + 2) * RP + r4]);
            const float4 f3 = *reinterpret_cast<const float4*>(&FT[(k + 3) * RP + r4]);
            #pragma unroll
            for (int j = 0; j < 7; j++) {
                const int n = nc + 32 * j;
                if (n < FFDIM) {
                    const float4 w = *reinterpret_cast<const float4*>(
                        w1 + (size_t)n * NF + k);
                    acc[j][0] += w.x * f0.x + w.y * f1.x + w.z * f2.x + w.w * f3.x;
                    acc[j][1] += w.x * f0.y + w.y * f1.y + w.z * f2.y + w.w * f3.y;
                    acc[j][2] += w.x * f0.z + w.y * f1.z + w.z * f2.z + w.w * f3.z;
                    acc[j][3] += w.x * f0.w + w.y * f1.w + w.z * f2.w + w.w * f3.w;
                }
            }
        }
        #pragma unroll
        for (int j = 0; j < 7; j++) {
            const int n = nc + 32 * j;
            if (n < FFDIM) {
                const float bb = b1[n];
                #pragma unroll
                for (int rr = 0; rr < 4; rr++) {
                    const float h = acc[j][rr] + bb;
                    HT[n * RP + r4 + rr] = h > 0.0f ? h : 0.0f;
                }
            }
        }
    }
    __syncthreads();

    // Phase C: out[r][o] = b2[o] + sum_k h[r][k] * w2[o][k]
    {
        const int r = tid & 31;
        const int og = tid >> 5;     // 0..7
        for (int p = 0; p < 2; p++) {
            const int o = og + 8 * p;
            if (o < NOUT) {
                float a = b2[o];
                for (int k = 0; k < FFDIM; k++)
                    a += HT[k * RP + r] * w2[(size_t)o * FFDIM + k];
                s_out[r * 16 + o] = a;
            }
        }
    }
    __syncthreads();

    if (SELECT) {
        if (tid < RB) {              // per-row top-6 (ties -> lowest index), sorted asc
            float sc[10];
            #pragma unroll
            for (int o = 0; o < 10; o++) sc[o] = s_out[tid * 16 + o];
            bool used[10];
            #pragma unroll
            for (int o = 0; o < 10; o++) used[o] = false;
            int ids[6];
            for (int k = 0; k < 6; k++) {
                float m = -3.0e38f; int mi = 0;
                for (int o = 0; o < 10; o++)
                    if (!used[o] && sc[o] > m) { m = sc[o]; mi = o; }
                used[mi] = true; ids[k] = mi;
            }
            for (int a2 = 1; a2 < 6; a2++) {     // insertion sort ascending
                const int v = ids[a2]; int bp = a2 - 1;
                while (bp >= 0 && ids[bp] > v) { ids[bp + 1] = ids[bp]; bp--; }
                ids[bp + 1] = v;
            }
            #pragma unroll
            for (int k = 0; k < 6; k++) s_idx[tid * 6 + k] = ids[k];
        }
        __syncthreads();
        for (int q = tid; q < RB * 24; q += 256) {
            const int r2 = q / 24, rem = q % 24, j = rem >> 2, c = rem & 3;
            selout[(size_t)blk * RB * 24 + q] =
                vectors[((size_t)(blk * RB + r2) * NJ + s_idx[r2 * 6 + j]) * 4 + c];
        }
    }

    for (int q = tid; q < RB * NOUT; q += 256) {
        const int r2 = q / NOUT, o = q % NOUT;
        out[(size_t)(blk * RB + r2) * OUTSTRIDE + out_off + o] = s_out[r2 * 16 + o];
    }
}

extern "C" void kernel_launch(void* const* d_in, const int* in_sizes, int n_in,
                              void* d_out, int out_size, void* d_ws, size_t ws_size,
                              hipStream_t stream) {
    const float* vectors  = (const float*)d_in[0];
    const float* isr_cola = (const float*)d_in[1];
    const float* isr_we   = (const float*)d_in[2];
    const float* isr_wd   = (const float*)d_in[3];
    const float* isr_bn_g = (const float*)d_in[4];
    const float* isr_bn_b = (const float*)d_in[5];
    const float* isr_w1   = (const float*)d_in[6];
    const float* isr_b1   = (const float*)d_in[7];
    const float* isr_w2   = (const float*)d_in[8];
    const float* isr_b2   = (const float*)d_in[9];
    const float* dec_cola = (const float*)d_in[10];
    const float* dec_we   = (const float*)d_in[11];
    const float* dec_wd   = (const float*)d_in[12];
    const float* dec_bn_g = (const float*)d_in[13];
    const float* dec_bn_b = (const float*)d_in[14];
    const float* dec_w1   = (const float*)d_in[15];
    const float* dec_b1   = (const float*)d_in[16];
    const float* dec_w2   = (const float*)d_in[17];
    const float* dec_b2   = (const float*)d_in[18];
    float* out = (float*)d_out;
    float* ws  = (float*)d_ws;

    // workspace layout (floats); f_buf is reused by both heads (~29.4 MB total)
    float* f_buf  = ws;                    // max(32768*160, 32768*140) = 5,242,880
    float* sel    = f_buf + 5242880;       // 32768*24 = 786,432
    float* ps     = sel + 786432;          // 4096*160 max = 655,360
    float* pq     = ps + 655360;           // 655,360
    float* bn_i   = pq + 655360;           // 320
    float* bn_d   = bn_i + 320;            // 280

    feat_kernel<10, 32><<<4096, 256, 0, stream>>>(vectors, isr_cola, isr_we, isr_wd,
                                                  f_buf, ps, pq);
    bn_reduce<160><<<160, 256, 0, stream>>>(ps, pq, 4096, isr_bn_g, isr_bn_b, bn_i);
    mlp_kernel<160, 10, true><<<1024, 256, 0, stream>>>(f_buf, bn_i, isr_w1, isr_b1,
                                                        isr_w2, isr_b2, vectors, sel,
                                                        out, 0);
    feat_kernel<6, 28><<<4096, 256, 0, stream>>>(sel, dec_cola, dec_we, dec_wd,
                                                 f_buf, ps, pq);
    bn_reduce<140><<<140, 256, 0, stream>>>(ps, pq, 4096, dec_bn_g, dec_bn_b, bn_d);
    mlp_kernel<140, 11, false><<<1024, 256, 0, stream>>>(f_buf, bn_d, dec_w1, dec_b1,
                                                         dec_w2, dec_b2, nullptr, nullptr,
                                                         out, 10);
}

// Round 2
// 175.138 us; speedup vs baseline: 1.7585x; 1.7585x over previous
//
#include <hip/hip_runtime.h>

// Hydra_56633438765296: two-head LoLa/CoLa jet network, fp32 (no fp32 MFMA on CDNA4;
// rank-sensitive top-6 between heads keeps us in fp32 vector math).
// R1 counters: mlp latency-bound (VALUBusy 20%, occ 25%, LDS 52KB -> 3 blk/CU,
// 1.9M bank conflicts from transpose-write). Fixes: FT/HT LDS union (32.4KB),
// block-transposed feature layout (coalesced + conflict-free Phase A),
// padded s_we/s_wd (was 32-way conflict), transposed BN partials.

#define BATCH 32768
#define NJ 10
#define FFDIM 200
#define OUTSTRIDE 21
#define NFEATBLK 4096

// ---------------- features kernel: cola + lola + BN partials ----------------
// NIN input 4-vectors, NP = NIN + 22 particles, F = NP*5 features.
// fout layout: [B/32][F][32] (block-transposed for the mlp kernel).
template<int NIN, int NP>
__global__ __launch_bounds__(256) void feat_kernel(
    const float* __restrict__ vin,    // [B][NIN][4]
    const float* __restrict__ cola,   // [22][NIN]
    const float* __restrict__ we,     // [NP][NP]
    const float* __restrict__ wd,     // [NP][NP]
    float* __restrict__ fout,         // [B/32][F][32]
    float* __restrict__ psum,         // [F][4096]
    float* __restrict__ psq)          // [F][4096]
{
    constexpr int NC = 22;
    constexpr int F  = NP * 5;
    constexpr int RB = 8;             // rows per block
    constexpr int SW = NP + 1;        // odd stride -> conflict-free i-indexed reads
    constexpr int SF = F + 8;         // 2-way max on transposed readout
    __shared__ float s_cola[NC * NIN];
    __shared__ float s_we[NP * SW];
    __shared__ float s_wd[NP * SW];
    __shared__ float4 s_x[RB][NP];
    __shared__ float s_m2[RB][NP];
    __shared__ float s_f[RB * SF];

    const int tid = threadIdx.x;
    const int blk = blockIdx.x;

    for (int k = tid; k < NC * NIN; k += 256) s_cola[k] = cola[k];
    for (int k = tid; k < NP * NP; k += 256) {
        const int i2 = k / NP, j2 = k - i2 * NP;
        s_we[i2 * SW + j2] = we[k];
        s_wd[i2 * SW + j2] = wd[k];
    }
    for (int k = tid; k < RB * NIN * 4; k += 256)
        ((float*)&s_x[0][0])[(k / (NIN * 4)) * NP * 4 + (k % (NIN * 4))] =
            vin[(size_t)blk * RB * NIN * 4 + k];
    __syncthreads();

    const int r = tid >> 5;          // row in block (8)
    const int i = tid & 31;          // particle slot

    if (i >= NIN && i < NP) {        // learned combos
        const int c = i - NIN;
        float4 x = make_float4(0.f, 0.f, 0.f, 0.f);
        #pragma unroll
        for (int j = 0; j < NIN; j++) {
            const float w = s_cola[c * NIN + j];
            const float4 xj = s_x[r][j];
            x.x += w * xj.x; x.y += w * xj.y; x.z += w * xj.z; x.w += w * xj.w;
        }
        s_x[r][i] = x;
    }
    __syncthreads();

    float m2 = 0.f, pt = 0.f;
    float4 xi = make_float4(0.f, 0.f, 0.f, 0.f);
    if (i < NP) {
        xi = s_x[r][i];
        m2 = xi.x * xi.x - xi.y * xi.y - xi.z * xi.z - xi.w * xi.w;
        pt = sqrtf(xi.y * xi.y + xi.z * xi.z);
        s_m2[r][i] = m2;
    }
    __syncthreads();
    if (i < NP) {
        float wesum = 0.f, wdsum = 0.f;
        for (int j = 0; j < NP; j++) {
            const float4 xj = s_x[r][j];                    // broadcast b128
            wesum += s_we[i * SW + j] * xj.x;               // conflict-free
            const float g = xi.x * xj.x - xi.y * xj.y - xi.z * xj.z - xi.w * xj.w;
            wdsum += s_wd[i * SW + j] * (m2 + s_m2[r][j] - 2.0f * g);
        }
        s_f[r * SF + i * 5 + 0] = m2;
        s_f[r * SF + i * 5 + 1] = pt;
        s_f[r * SF + i * 5 + 2] = xi.x;
        s_f[r * SF + i * 5 + 3] = wesum;
        s_f[r * SF + i * 5 + 4] = wdsum;
    }
    __syncthreads();

    // block-transposed write: fout[blk>>2][c][(blk&3)*8 + rr]
    const size_t base = (size_t)(blk >> 2) * F * 32 + (blk & 3) * 8;
    for (int q = tid; q < F * RB; q += 256) {
        const int c = q >> 3, rr = q & 7;
        fout[base + (size_t)c * 32 + rr] = s_f[rr * SF + c];
    }

    if (tid < F) {                   // per-block BN partials (deterministic)
        float s = 0.f, s2 = 0.f;
        #pragma unroll
        for (int rr = 0; rr < RB; rr++) {
            const float v = s_f[rr * SF + tid];
            s += v; s2 += v * v;
        }
        psum[(size_t)tid * NFEATBLK + blk] = s;
        psq [(size_t)tid * NFEATBLK + blk] = s2;
    }
}

// ---------------- BN reduce: partials -> per-feature scale/shift ----------------
template<int F>
__global__ __launch_bounds__(256) void bn_reduce(
    const float* __restrict__ psum, const float* __restrict__ psq,
    const float* __restrict__ gamma, const float* __restrict__ beta,
    float* __restrict__ bn)          // [2*F]: scale then shift
{
    __shared__ float s1[256], s2[256];
    const int f = blockIdx.x, tid = threadIdx.x;
    float a = 0.f, b = 0.f;
    for (int bk = tid; bk < NFEATBLK; bk += 256) {   // coalesced (transposed layout)
        a += psum[(size_t)f * NFEATBLK + bk];
        b += psq [(size_t)f * NFEATBLK + bk];
    }
    s1[tid] = a; s2[tid] = b; __syncthreads();
    for (int s = 128; s > 0; s >>= 1) {
        if (tid < s) { s1[tid] += s1[tid + s]; s2[tid] += s2[tid + s]; }
        __syncthreads();
    }
    if (tid == 0) {
        const float mu  = s1[0] / (float)BATCH;
        const float var = s2[0] / (float)BATCH - mu * mu;
        const float sc  = gamma[f] * rsqrtf(var + 1e-5f);
        bn[f]     = sc;
        bn[F + f] = beta[f] - mu * sc;
    }
}

// ---------------- MLP kernel: BN affine + FC1(relu) + FC2 (+ top-6 select) ----------------
// LDS union: U holds FT [NF][36] during FC1, then HT [200][36] (acc lives in regs
// across the swap). 32.4KB LDS -> 4-5 blocks/CU (was 52KB -> 3).
template<int NF, int NOUT, bool SELECT>
__global__ __launch_bounds__(256, 4) void mlp_kernel(
    const float* __restrict__ fin,   // [B/32][NF][32] block-transposed
    const float* __restrict__ bn,    // [2*NF]
    const float* __restrict__ w1,    // [200][NF]
    const float* __restrict__ b1,    // [200]
    const float* __restrict__ w2,    // [NOUT][200]
    const float* __restrict__ b2,    // [NOUT]
    const float* __restrict__ vectors, // [B][10][4] (SELECT only)
    float* __restrict__ selout,      // [B][6][4]   (SELECT only)
    float* __restrict__ out,         // [B][21]
    int out_off)
{
    constexpr int RB = 32;
    constexpr int RP = 36;           // row stride (16B-aligned, conflict-free)
    __shared__ __align__(16) float U[FFDIM * RP];
    __shared__ float s_scale[NF], s_shift[NF];
    __shared__ float s_out[RB * 12];
    __shared__ int   s_idx[RB * 6];

    const int tid = threadIdx.x;
    const int blk = blockIdx.x;

    for (int k = tid; k < NF; k += 256) { s_scale[k] = bn[k]; s_shift[k] = bn[NF + k]; }
    __syncthreads();

    // Phase A: coalesced read of transposed features, BN affine, conflict-free LDS write.
    const float* fb = fin + (size_t)blk * NF * 32;
    for (int q = tid; q < NF * 32; q += 256) {
        const int c = q >> 5, r = q & 31;
        U[c * RP + r] = fb[q] * s_scale[c] + s_shift[c];
    }
    __syncthreads();

    // Phase B: H = relu(W1 @ f + b1). Thread = 4 rows x 7 neurons, all H in regs.
    const int rg = tid & 7, r4 = rg * 4, nc = tid >> 3;
    float acc[7][4];
    #pragma unroll
    for (int j = 0; j < 7; j++)
        #pragma unroll
        for (int rr = 0; rr < 4; rr++) acc[j][rr] = 0.0f;

    constexpr int NF4 = NF / 4;
    for (int kc = 0; kc < NF4; kc++) {
        const int k = kc * 4;
        const float4 f0 = *reinterpret_cast<const float4*>(&U[(k + 0) * RP + r4]);
        const float4 f1 = *reinterpret_cast<const float4*>(&U[(k + 1) * RP + r4]);
        const float4 f2 = *reinterpret_cast<const float4*>(&U[(k + 2) * RP + r4]);
        const float4 f3 = *reinterpret_cast<const float4*>(&U[(k + 3) * RP + r4]);
        float4 w[7];
        #pragma unroll
        for (int j = 0; j < 6; j++)
            w[j] = *reinterpret_cast<const float4*>(w1 + (size_t)(nc + 32 * j) * NF + k);
        w[6] = (nc < FFDIM - 192)
             ? *reinterpret_cast<const float4*>(w1 + (size_t)(nc + 192) * NF + k)
             : make_float4(0.f, 0.f, 0.f, 0.f);
        #pragma unroll
        for (int j = 0; j < 7; j++) {
            acc[j][0] += w[j].x * f0.x + w[j].y * f1.x + w[j].z * f2.x + w[j].w * f3.x;
            acc[j][1] += w[j].x * f0.y + w[j].y * f1.y + w[j].z * f2.y + w[j].w * f3.y;
            acc[j][2] += w[j].x * f0.z + w[j].y * f1.z + w[j].z * f2.z + w[j].w * f3.z;
            acc[j][3] += w[j].x * f0.w + w[j].y * f1.w + w[j].z * f2.w + w[j].w * f3.w;
        }
    }
    __syncthreads();                 // all waves done reading U as FT

    #pragma unroll
    for (int j = 0; j < 7; j++) {
        const int n = nc + 32 * j;
        if (n < FFDIM) {
            const float bb = b1[n];
            float4 h;
            h.x = acc[j][0] + bb; h.x = h.x > 0.f ? h.x : 0.f;
            h.y = acc[j][1] + bb; h.y = h.y > 0.f ? h.y : 0.f;
            h.z = acc[j][2] + bb; h.z = h.z > 0.f ? h.z : 0.f;
            h.w = acc[j][3] + bb; h.w = h.w > 0.f ? h.w : 0.f;
            *reinterpret_cast<float4*>(&U[n * RP + r4]) = h;  // uniform 8-cyc write
        }
    }
    __syncthreads();

    // Phase C: out[r][o] = b2[o] + sum_k h[r][k] * w2[o][k]
    {
        const int r = tid & 31, og = tid >> 5;
        for (int o = og; o < NOUT; o += 8) {
            float a = b2[o];
            for (int kc = 0; kc < FFDIM / 4; kc++) {
                const float4 wv = *reinterpret_cast<const float4*>(
                    w2 + (size_t)o * FFDIM + kc * 4);
                a += wv.x * U[(kc * 4 + 0) * RP + r] + wv.y * U[(kc * 4 + 1) * RP + r]
                   + wv.z * U[(kc * 4 + 2) * RP + r] + wv.w * U[(kc * 4 + 3) * RP + r];
            }
            s_out[r * 12 + o] = a;
        }
    }
    __syncthreads();

    if (SELECT) {
        if (tid < RB) {              // per-row top-6 (ties -> lowest index), sorted asc
            float sc[10];
            #pragma unroll
            for (int o = 0; o < 10; o++) sc[o] = s_out[tid * 12 + o];
            bool used[10];
            #pragma unroll
            for (int o = 0; o < 10; o++) used[o] = false;
            int ids[6];
            for (int k = 0; k < 6; k++) {
                float m = -3.0e38f; int mi = 0;
                for (int o = 0; o < 10; o++)
                    if (!used[o] && sc[o] > m) { m = sc[o]; mi = o; }
                used[mi] = true; ids[k] = mi;
            }
            for (int a2 = 1; a2 < 6; a2++) {     // insertion sort ascending
                const int v = ids[a2]; int bp = a2 - 1;
                while (bp >= 0 && ids[bp] > v) { ids[bp + 1] = ids[bp]; bp--; }
                ids[bp + 1] = v;
            }
            #pragma unroll
            for (int k = 0; k < 6; k++) s_idx[tid * 6 + k] = ids[k];
        }
        __syncthreads();
        for (int q = tid; q < RB * 6; q += 256) {    // float4 gather of selected jets
            const int r2 = q / 6, j = q - r2 * 6;
            reinterpret_cast<float4*>(selout)[(size_t)blk * RB * 6 + q] =
                reinterpret_cast<const float4*>(vectors)
                    [(size_t)(blk * RB + r2) * NJ + s_idx[r2 * 6 + j]];
        }
    }

    for (int q = tid; q < RB * NOUT; q += 256) {
        const int r2 = q / NOUT, o = q - r2 * NOUT;
        out[(size_t)(blk * RB + r2) * OUTSTRIDE + out_off + o] = s_out[r2 * 12 + o];
    }
}

extern "C" void kernel_launch(void* const* d_in, const int* in_sizes, int n_in,
                              void* d_out, int out_size, void* d_ws, size_t ws_size,
                              hipStream_t stream) {
    const float* vectors  = (const float*)d_in[0];
    const float* isr_cola = (const float*)d_in[1];
    const float* isr_we   = (const float*)d_in[2];
    const float* isr_wd   = (const float*)d_in[3];
    const float* isr_bn_g = (const float*)d_in[4];
    const float* isr_bn_b = (const float*)d_in[5];
    const float* isr_w1   = (const float*)d_in[6];
    const float* isr_b1   = (const float*)d_in[7];
    const float* isr_w2   = (const float*)d_in[8];
    const float* isr_b2   = (const float*)d_in[9];
    const float* dec_cola = (const float*)d_in[10];
    const float* dec_we   = (const float*)d_in[11];
    const float* dec_wd   = (const float*)d_in[12];
    const float* dec_bn_g = (const float*)d_in[13];
    const float* dec_bn_b = (const float*)d_in[14];
    const float* dec_w1   = (const float*)d_in[15];
    const float* dec_b1   = (const float*)d_in[16];
    const float* dec_w2   = (const float*)d_in[17];
    const float* dec_b2   = (const float*)d_in[18];
    float* out = (float*)d_out;
    float* ws  = (float*)d_ws;

    // workspace layout (floats); f_buf reused by both heads (~29.4 MB total)
    float* f_buf  = ws;                    // 32768*160 = 5,242,880
    float* sel    = f_buf + 5242880;       // 32768*24 = 786,432
    float* ps     = sel + 786432;          // 160*4096 = 655,360
    float* pq     = ps + 655360;           // 655,360
    float* bn_i   = pq + 655360;           // 320
    float* bn_d   = bn_i + 320;            // 280

    feat_kernel<10, 32><<<4096, 256, 0, stream>>>(vectors, isr_cola, isr_we, isr_wd,
                                                  f_buf, ps, pq);
    bn_reduce<160><<<160, 256, 0, stream>>>(ps, pq, isr_bn_g, isr_bn_b, bn_i);
    mlp_kernel<160, 10, true><<<1024, 256, 0, stream>>>(f_buf, bn_i, isr_w1, isr_b1,
                                                        isr_w2, isr_b2, vectors, sel,
                                                        out, 0);
    feat_kernel<6, 28><<<4096, 256, 0, stream>>>(sel, dec_cola, dec_we, dec_wd,
                                                 f_buf, ps, pq);
    bn_reduce<140><<<140, 256, 0, stream>>>(ps, pq, dec_bn_g, dec_bn_b, bn_d);
    mlp_kernel<140, 11, false><<<1024, 256, 0, stream>>>(f_buf, bn_d, dec_w1, dec_b1,
                                                         dec_w2, dec_b2, nullptr, nullptr,
                                                         out, 10);
}

// Round 3
// 173.846 us; speedup vs baseline: 1.7716x; 1.0074x over previous
//
#include <hip/hip_runtime.h>

// Hydra_56633438765296: two-head LoLa/CoLa jet network, fp32 (no fp32 MFMA on CDNA4;
// rank-sensitive top-6 between heads keeps us in fp32 vector math).
// R2 counters: mlp 65us each, VALUBusy 46%, occ 33%, HBM 2.8% -> issue/latency bound.
// R3: v_pk_fma_f32 via <2 x float> (fp32 peak 157TF needs packed; scalar caps at 78.6TF)
//     + manual weight prefetch (wcur/wnxt) to hide L2 latency under the FMA block.

#define BATCH 32768
#define NJ 10
#define FFDIM 200
#define OUTSTRIDE 21
#define NFEATBLK 4096

typedef float v2f __attribute__((ext_vector_type(2)));

// ---------------- features kernel: cola + lola + BN partials ----------------
template<int NIN, int NP>
__global__ __launch_bounds__(256) void feat_kernel(
    const float* __restrict__ vin,    // [B][NIN][4]
    const float* __restrict__ cola,   // [22][NIN]
    const float* __restrict__ we,     // [NP][NP]
    const float* __restrict__ wd,     // [NP][NP]
    float* __restrict__ fout,         // [B/32][F][32]
    float* __restrict__ psum,         // [F][4096]
    float* __restrict__ psq)          // [F][4096]
{
    constexpr int NC = 22;
    constexpr int F  = NP * 5;
    constexpr int RB = 8;             // rows per block
    constexpr int SW = NP + 1;        // odd stride -> conflict-free i-indexed reads
    constexpr int SF = F + 8;         // 2-way max on transposed readout
    __shared__ float s_cola[NC * NIN];
    __shared__ float s_we[NP * SW];
    __shared__ float s_wd[NP * SW];
    __shared__ float4 s_x[RB][NP];
    __shared__ float s_m2[RB][NP];
    __shared__ float s_f[RB * SF];

    const int tid = threadIdx.x;
    const int blk = blockIdx.x;

    for (int k = tid; k < NC * NIN; k += 256) s_cola[k] = cola[k];
    for (int k = tid; k < NP * NP; k += 256) {
        const int i2 = k / NP, j2 = k - i2 * NP;
        s_we[i2 * SW + j2] = we[k];
        s_wd[i2 * SW + j2] = wd[k];
    }
    for (int k = tid; k < RB * NIN * 4; k += 256)
        ((float*)&s_x[0][0])[(k / (NIN * 4)) * NP * 4 + (k % (NIN * 4))] =
            vin[(size_t)blk * RB * NIN * 4 + k];
    __syncthreads();

    const int r = tid >> 5;          // row in block (8)
    const int i = tid & 31;          // particle slot

    if (i >= NIN && i < NP) {        // learned combos
        const int c = i - NIN;
        float4 x = make_float4(0.f, 0.f, 0.f, 0.f);
        #pragma unroll
        for (int j = 0; j < NIN; j++) {
            const float w = s_cola[c * NIN + j];
            const float4 xj = s_x[r][j];
            x.x += w * xj.x; x.y += w * xj.y; x.z += w * xj.z; x.w += w * xj.w;
        }
        s_x[r][i] = x;
    }
    __syncthreads();

    float m2 = 0.f, pt = 0.f;
    float4 xi = make_float4(0.f, 0.f, 0.f, 0.f);
    if (i < NP) {
        xi = s_x[r][i];
        m2 = xi.x * xi.x - xi.y * xi.y - xi.z * xi.z - xi.w * xi.w;
        pt = sqrtf(xi.y * xi.y + xi.z * xi.z);
        s_m2[r][i] = m2;
    }
    __syncthreads();
    if (i < NP) {
        float wesum = 0.f, wdsum = 0.f;
        for (int j = 0; j < NP; j++) {
            const float4 xj = s_x[r][j];                    // broadcast b128
            wesum += s_we[i * SW + j] * xj.x;               // conflict-free
            const float g = xi.x * xj.x - xi.y * xj.y - xi.z * xj.z - xi.w * xj.w;
            wdsum += s_wd[i * SW + j] * (m2 + s_m2[r][j] - 2.0f * g);
        }
        s_f[r * SF + i * 5 + 0] = m2;
        s_f[r * SF + i * 5 + 1] = pt;
        s_f[r * SF + i * 5 + 2] = xi.x;
        s_f[r * SF + i * 5 + 3] = wesum;
        s_f[r * SF + i * 5 + 4] = wdsum;
    }
    __syncthreads();

    // block-transposed write: fout[blk>>2][c][(blk&3)*8 + rr]
    const size_t base = (size_t)(blk >> 2) * F * 32 + (blk & 3) * 8;
    for (int q = tid; q < F * RB; q += 256) {
        const int c = q >> 3, rr = q & 7;
        fout[base + (size_t)c * 32 + rr] = s_f[rr * SF + c];
    }

    if (tid < F) {                   // per-block BN partials (deterministic)
        float s = 0.f, s2 = 0.f;
        #pragma unroll
        for (int rr = 0; rr < RB; rr++) {
            const float v = s_f[rr * SF + tid];
            s += v; s2 += v * v;
        }
        psum[(size_t)tid * NFEATBLK + blk] = s;
        psq [(size_t)tid * NFEATBLK + blk] = s2;
    }
}

// ---------------- BN reduce: partials -> per-feature scale/shift ----------------
template<int F>
__global__ __launch_bounds__(256) void bn_reduce(
    const float* __restrict__ psum, const float* __restrict__ psq,
    const float* __restrict__ gamma, const float* __restrict__ beta,
    float* __restrict__ bn)          // [2*F]: scale then shift
{
    __shared__ float s1[256], s2[256];
    const int f = blockIdx.x, tid = threadIdx.x;
    float a = 0.f, b = 0.f;
    for (int bk = tid; bk < NFEATBLK; bk += 256) {
        a += psum[(size_t)f * NFEATBLK + bk];
        b += psq [(size_t)f * NFEATBLK + bk];
    }
    s1[tid] = a; s2[tid] = b; __syncthreads();
    for (int s = 128; s > 0; s >>= 1) {
        if (tid < s) { s1[tid] += s1[tid + s]; s2[tid] += s2[tid + s]; }
        __syncthreads();
    }
    if (tid == 0) {
        const float mu  = s1[0] / (float)BATCH;
        const float var = s2[0] / (float)BATCH - mu * mu;
        const float sc  = gamma[f] * rsqrtf(var + 1e-5f);
        bn[f]     = sc;
        bn[F + f] = beta[f] - mu * sc;
    }
}

// ---------------- MLP kernel: BN affine + FC1(relu) + FC2 (+ top-6 select) ----------------
template<int NF, int NOUT, bool SELECT>
__global__ __launch_bounds__(256, 4) void mlp_kernel(
    const float* __restrict__ fin,   // [B/32][NF][32] block-transposed
    const float* __restrict__ bn,    // [2*NF]
    const float* __restrict__ w1,    // [200][NF]
    const float* __restrict__ b1,    // [200]
    const float* __restrict__ w2,    // [NOUT][200]
    const float* __restrict__ b2,    // [NOUT]
    const float* __restrict__ vectors, // [B][10][4] (SELECT only)
    float* __restrict__ selout,      // [B][6][4]   (SELECT only)
    float* __restrict__ out,         // [B][21]
    int out_off)
{
    constexpr int RB = 32;
    constexpr int RP = 36;           // row stride (16B-aligned, conflict-free reads)
    __shared__ __align__(16) float U[FFDIM * RP];
    __shared__ float s_scale[NF], s_shift[NF];
    __shared__ float s_out[RB * 12];
    __shared__ int   s_idx[RB * 6];

    const int tid = threadIdx.x;
    const int blk = blockIdx.x;

    for (int k = tid; k < NF; k += 256) { s_scale[k] = bn[k]; s_shift[k] = bn[NF + k]; }
    __syncthreads();

    // Phase A: coalesced float4 read of transposed features, BN affine, LDS write.
    {
        const float4* fb4 = reinterpret_cast<const float4*>(fin + (size_t)blk * NF * 32);
        for (int q4 = tid; q4 < NF * 8; q4 += 256) {
            const int c = q4 >> 3, r4a = (q4 & 7) * 4;
            const float4 v = fb4[q4];
            const float sc = s_scale[c], sh = s_shift[c];
            float4 o;
            o.x = v.x * sc + sh; o.y = v.y * sc + sh;
            o.z = v.z * sc + sh; o.w = v.w * sc + sh;
            *reinterpret_cast<float4*>(&U[c * RP + r4a]) = o;
        }
    }
    __syncthreads();

    // Phase B: H = relu(W1 @ f + b1). Thread = 4 rows x 7 neurons.
    // Packed v2f accumulators (v_pk_fma_f32) + manual weight prefetch.
    const int r4 = (tid & 7) * 4;
    const int nc = tid >> 3;
    const int n6ok = (nc < FFDIM - 192);     // neuron 192+nc exists?

    const float* wrow[7];
    float bb[7];
    #pragma unroll
    for (int j = 0; j < 6; j++) {
        wrow[j] = w1 + (size_t)(nc + 32 * j) * NF;
        bb[j] = b1[nc + 32 * j];
    }
    wrow[6] = w1 + (size_t)(n6ok ? (nc + 192) : nc) * NF;   // dummy row if absent
    bb[6] = n6ok ? b1[nc + 192] : 0.f;

    v2f acc[7][2];
    #pragma unroll
    for (int j = 0; j < 7; j++) { acc[j][0] = (v2f){0.f, 0.f}; acc[j][1] = (v2f){0.f, 0.f}; }

    constexpr int NF4 = NF / 4;
    float4 wcur[7], wnxt[7];
    #pragma unroll
    for (int j = 0; j < 7; j++)
        wcur[j] = *reinterpret_cast<const float4*>(wrow[j]);

    for (int kc = 0; kc < NF4; kc++) {
        const int k = kc * 4;
        const int kn = (kc + 1 < NF4) ? (k + 4) : k;        // clamp last prefetch
        #pragma unroll
        for (int j = 0; j < 7; j++)
            wnxt[j] = *reinterpret_cast<const float4*>(wrow[j] + kn);

        const float4 f0 = *reinterpret_cast<const float4*>(&U[(k + 0) * RP + r4]);
        const float4 f1 = *reinterpret_cast<const float4*>(&U[(k + 1) * RP + r4]);
        const float4 f2 = *reinterpret_cast<const float4*>(&U[(k + 2) * RP + r4]);
        const float4 f3 = *reinterpret_cast<const float4*>(&U[(k + 3) * RP + r4]);
        const v2f f0l = (v2f){f0.x, f0.y}, f0h = (v2f){f0.z, f0.w};
        const v2f f1l = (v2f){f1.x, f1.y}, f1h = (v2f){f1.z, f1.w};
        const v2f f2l = (v2f){f2.x, f2.y}, f2h = (v2f){f2.z, f2.w};
        const v2f f3l = (v2f){f3.x, f3.y}, f3h = (v2f){f3.z, f3.w};

        #pragma unroll
        for (int j = 0; j < 7; j++) {
            const v2f wx = (v2f){wcur[j].x, wcur[j].x};
            const v2f wy = (v2f){wcur[j].y, wcur[j].y};
            const v2f wz = (v2f){wcur[j].z, wcur[j].z};
            const v2f ww = (v2f){wcur[j].w, wcur[j].w};
            acc[j][0] += wx * f0l; acc[j][0] += wy * f1l;
            acc[j][0] += wz * f2l; acc[j][0] += ww * f3l;
            acc[j][1] += wx * f0h; acc[j][1] += wy * f1h;
            acc[j][1] += wz * f2h; acc[j][1] += ww * f3h;
        }
        #pragma unroll
        for (int j = 0; j < 7; j++) wcur[j] = wnxt[j];
    }
    __syncthreads();                 // all waves done reading U as FT

    #pragma unroll
    for (int j = 0; j < 7; j++) {
        if (j < 6 || n6ok) {
            const int n = nc + 32 * j;
            float4 h;
            h.x = acc[j][0][0] + bb[j]; h.x = h.x > 0.f ? h.x : 0.f;
            h.y = acc[j][0][1] + bb[j]; h.y = h.y > 0.f ? h.y : 0.f;
            h.z = acc[j][1][0] + bb[j]; h.z = h.z > 0.f ? h.z : 0.f;
            h.w = acc[j][1][1] + bb[j]; h.w = h.w > 0.f ? h.w : 0.f;
            *reinterpret_cast<float4*>(&U[n * RP + r4]) = h;
        }
    }
    __syncthreads();

    // Phase C: out[r][o] = b2[o] + sum_k h[r][k] * w2[o][k]  (packed pairs over k)
    {
        const int r = tid & 31, og = tid >> 5;
        for (int o = og; o < NOUT; o += 8) {
            v2f a2 = (v2f){b2[o], 0.f};
            const v2f* w2p = reinterpret_cast<const v2f*>(w2 + (size_t)o * FFDIM);
            for (int kp = 0; kp < FFDIM / 2; kp++) {
                const v2f hh = (v2f){U[(2 * kp) * RP + r], U[(2 * kp + 1) * RP + r]};
                a2 += w2p[kp] * hh;
            }
            s_out[r * 12 + o] = a2[0] + a2[1];
        }
    }
    __syncthreads();

    if (SELECT) {
        if (tid < RB) {              // per-row top-6 (ties -> lowest index), sorted asc
            float sc[10];
            #pragma unroll
            for (int o = 0; o < 10; o++) sc[o] = s_out[tid * 12 + o];
            bool used[10];
            #pragma unroll
            for (int o = 0; o < 10; o++) used[o] = false;
            int ids[6];
            for (int k = 0; k < 6; k++) {
                float m = -3.0e38f; int mi = 0;
                for (int o = 0; o < 10; o++)
                    if (!used[o] && sc[o] > m) { m = sc[o]; mi = o; }
                used[mi] = true; ids[k] = mi;
            }
            for (int a2i = 1; a2i < 6; a2i++) {  // insertion sort ascending
                const int v = ids[a2i]; int bp = a2i - 1;
                while (bp >= 0 && ids[bp] > v) { ids[bp + 1] = ids[bp]; bp--; }
                ids[bp + 1] = v;
            }
            #pragma unroll
            for (int k = 0; k < 6; k++) s_idx[tid * 6 + k] = ids[k];
        }
        __syncthreads();
        for (int q = tid; q < RB * 6; q += 256) {    // float4 gather of selected jets
            const int r2 = q / 6, j = q - r2 * 6;
            reinterpret_cast<float4*>(selout)[(size_t)blk * RB * 6 + q] =
                reinterpret_cast<const float4*>(vectors)
                    [(size_t)(blk * RB + r2) * NJ + s_idx[r2 * 6 + j]];
        }
    }

    for (int q = tid; q < RB * NOUT; q += 256) {
        const int r2 = q / NOUT, o = q - r2 * NOUT;
        out[(size_t)(blk * RB + r2) * OUTSTRIDE + out_off + o] = s_out[r2 * 12 + o];
    }
}

extern "C" void kernel_launch(void* const* d_in, const int* in_sizes, int n_in,
                              void* d_out, int out_size, void* d_ws, size_t ws_size,
                              hipStream_t stream) {
    const float* vectors  = (const float*)d_in[0];
    const float* isr_cola = (const float*)d_in[1];
    const float* isr_we   = (const float*)d_in[2];
    const float* isr_wd   = (const float*)d_in[3];
    const float* isr_bn_g = (const float*)d_in[4];
    const float* isr_bn_b = (const float*)d_in[5];
    const float* isr_w1   = (const float*)d_in[6];
    const float* isr_b1   = (const float*)d_in[7];
    const float* isr_w2   = (const float*)d_in[8];
    const float* isr_b2   = (const float*)d_in[9];
    const float* dec_cola = (const float*)d_in[10];
    const float* dec_we   = (const float*)d_in[11];
    const float* dec_wd   = (const float*)d_in[12];
    const float* dec_bn_g = (const float*)d_in[13];
    const float* dec_bn_b = (const float*)d_in[14];
    const float* dec_w1   = (const float*)d_in[15];
    const float* dec_b1   = (const float*)d_in[16];
    const float* dec_w2   = (const float*)d_in[17];
    const float* dec_b2   = (const float*)d_in[18];
    float* out = (float*)d_out;
    float* ws  = (float*)d_ws;

    // workspace layout (floats); f_buf reused by both heads (~29.4 MB total)
    float* f_buf  = ws;                    // 32768*160 = 5,242,880
    float* sel    = f_buf + 5242880;       // 32768*24 = 786,432
    float* ps     = sel + 786432;          // 160*4096 = 655,360
    float* pq     = ps + 655360;           // 655,360
    float* bn_i   = pq + 655360;           // 320
    float* bn_d   = bn_i + 320;            // 280

    feat_kernel<10, 32><<<4096, 256, 0, stream>>>(vectors, isr_cola, isr_we, isr_wd,
                                                  f_buf, ps, pq);
    bn_reduce<160><<<160, 256, 0, stream>>>(ps, pq, isr_bn_g, isr_bn_b, bn_i);
    mlp_kernel<160, 10, true><<<1024, 256, 0, stream>>>(f_buf, bn_i, isr_w1, isr_b1,
                                                        isr_w2, isr_b2, vectors, sel,
                                                        out, 0);
    feat_kernel<6, 28><<<4096, 256, 0, stream>>>(sel, dec_cola, dec_we, dec_wd,
                                                 f_buf, ps, pq);
    bn_reduce<140><<<140, 256, 0, stream>>>(ps, pq, dec_bn_g, dec_bn_b, bn_d);
    mlp_kernel<140, 11, false><<<1024, 256, 0, stream>>>(f_buf, bn_d, dec_w1, dec_b1,
                                                         dec_w2, dec_b2, nullptr, nullptr,
                                                         out, 10);
}

// Round 4
// 162.355 us; speedup vs baseline: 1.8970x; 1.0708x over previous
//
#include <hip/hip_runtime.h>

// Hydra_56633438765296: two-head LoLa/CoLa jet network, fp32 (no fp32 MFMA on CDNA4;
// rank-sensitive top-6 between heads keeps everything fp32 vector math).
// R3 post-mortem: mlp is L2-latency-bound; compiler sank the prefetch loads
// (VGPR=60 proves wcur/wnxt never coexisted). R4: FC1 retiled to 8 rows x 4 neurons
// per thread (128-cyc FMA block per 4 weight loads), explicit A/B weight double
// buffer with sched_barrier(0) pins so loads stay one FMA block ahead.

#define BATCH 32768
#define NJ 10
#define FFDIM 200
#define OUTSTRIDE 21
#define NFEATBLK 4096

typedef float v2f __attribute__((ext_vector_type(2)));

// ---------------- features kernel: cola + lola + BN partials ----------------
template<int NIN, int NP>
__global__ __launch_bounds__(256) void feat_kernel(
    const float* __restrict__ vin,    // [B][NIN][4]
    const float* __restrict__ cola,   // [22][NIN]
    const float* __restrict__ we,     // [NP][NP]
    const float* __restrict__ wd,     // [NP][NP]
    float* __restrict__ fout,         // [B/32][F][32]
    float* __restrict__ psum,         // [F][4096]
    float* __restrict__ psq)          // [F][4096]
{
    constexpr int NC = 22;
    constexpr int F  = NP * 5;
    constexpr int RB = 8;             // rows per block
    constexpr int SW = NP + 1;        // odd stride -> conflict-free i-indexed reads
    constexpr int SF = F + 8;         // 2-way max on transposed readout
    __shared__ float s_cola[NC * NIN];
    __shared__ float s_we[NP * SW];
    __shared__ float s_wd[NP * SW];
    __shared__ float4 s_x[RB][NP];
    __shared__ float s_m2[RB][NP];
    __shared__ float s_f[RB * SF];

    const int tid = threadIdx.x;
    const int blk = blockIdx.x;

    for (int k = tid; k < NC * NIN; k += 256) s_cola[k] = cola[k];
    for (int k = tid; k < NP * NP; k += 256) {
        const int i2 = k / NP, j2 = k - i2 * NP;
        s_we[i2 * SW + j2] = we[k];
        s_wd[i2 * SW + j2] = wd[k];
    }
    for (int k = tid; k < RB * NIN * 4; k += 256)
        ((float*)&s_x[0][0])[(k / (NIN * 4)) * NP * 4 + (k % (NIN * 4))] =
            vin[(size_t)blk * RB * NIN * 4 + k];
    __syncthreads();

    const int r = tid >> 5;          // row in block (8)
    const int i = tid & 31;          // particle slot

    if (i >= NIN && i < NP) {        // learned combos
        const int c = i - NIN;
        float4 x = make_float4(0.f, 0.f, 0.f, 0.f);
        #pragma unroll
        for (int j = 0; j < NIN; j++) {
            const float w = s_cola[c * NIN + j];
            const float4 xj = s_x[r][j];
            x.x += w * xj.x; x.y += w * xj.y; x.z += w * xj.z; x.w += w * xj.w;
        }
        s_x[r][i] = x;
    }
    __syncthreads();

    float m2 = 0.f, pt = 0.f;
    float4 xi = make_float4(0.f, 0.f, 0.f, 0.f);
    if (i < NP) {
        xi = s_x[r][i];
        m2 = xi.x * xi.x - xi.y * xi.y - xi.z * xi.z - xi.w * xi.w;
        pt = sqrtf(xi.y * xi.y + xi.z * xi.z);
        s_m2[r][i] = m2;
    }
    __syncthreads();
    if (i < NP) {
        float wesum = 0.f, wdsum = 0.f;
        for (int j = 0; j < NP; j++) {
            const float4 xj = s_x[r][j];                    // broadcast b128
            wesum += s_we[i * SW + j] * xj.x;               // conflict-free
            const float g = xi.x * xj.x - xi.y * xj.y - xi.z * xj.z - xi.w * xj.w;
            wdsum += s_wd[i * SW + j] * (m2 + s_m2[r][j] - 2.0f * g);
        }
        s_f[r * SF + i * 5 + 0] = m2;
        s_f[r * SF + i * 5 + 1] = pt;
        s_f[r * SF + i * 5 + 2] = xi.x;
        s_f[r * SF + i * 5 + 3] = wesum;
        s_f[r * SF + i * 5 + 4] = wdsum;
    }
    __syncthreads();

    // block-transposed write: fout[blk>>2][c][(blk&3)*8 + rr]
    const size_t base = (size_t)(blk >> 2) * F * 32 + (blk & 3) * 8;
    for (int q = tid; q < F * RB; q += 256) {
        const int c = q >> 3, rr = q & 7;
        fout[base + (size_t)c * 32 + rr] = s_f[rr * SF + c];
    }

    if (tid < F) {                   // per-block BN partials (deterministic)
        float s = 0.f, s2 = 0.f;
        #pragma unroll
        for (int rr = 0; rr < RB; rr++) {
            const float v = s_f[rr * SF + tid];
            s += v; s2 += v * v;
        }
        psum[(size_t)tid * NFEATBLK + blk] = s;
        psq [(size_t)tid * NFEATBLK + blk] = s2;
    }
}

// ---------------- BN reduce: partials -> per-feature scale/shift ----------------
template<int F>
__global__ __launch_bounds__(256) void bn_reduce(
    const float* __restrict__ psum, const float* __restrict__ psq,
    const float* __restrict__ gamma, const float* __restrict__ beta,
    float* __restrict__ bn)          // [2*F]: scale then shift
{
    __shared__ float s1[256], s2[256];
    const int f = blockIdx.x, tid = threadIdx.x;
    float a = 0.f, b = 0.f;
    for (int bk = tid; bk < NFEATBLK; bk += 256) {
        a += psum[(size_t)f * NFEATBLK + bk];
        b += psq [(size_t)f * NFEATBLK + bk];
    }
    s1[tid] = a; s2[tid] = b; __syncthreads();
    for (int s = 128; s > 0; s >>= 1) {
        if (tid < s) { s1[tid] += s1[tid + s]; s2[tid] += s2[tid + s]; }
        __syncthreads();
    }
    if (tid == 0) {
        const float mu  = s1[0] / (float)BATCH;
        const float var = s2[0] / (float)BATCH - mu * mu;
        const float sc  = gamma[f] * rsqrtf(var + 1e-5f);
        bn[f]     = sc;
        bn[F + f] = beta[f] - mu * sc;
    }
}

// ---------------- MLP kernel: BN affine + FC1(relu) + FC2 (+ top-6 select) ----------------
// Thread = 8 rows x 4 neurons. Weights double-buffered (wA/wB), loads pinned one
// 128-cycle FMA block ahead via sched_barrier(0).

// one k-slice: 2 LDS b128 feature reads + 16 pk-FMA (4 neurons x 4 row-pairs)
#define FMA_K(W, comp, k) do {                                               \
    const float4 fa = *reinterpret_cast<const float4*>(&U[(k) * RP + rp]);   \
    const float4 fb = *reinterpret_cast<const float4*>(&U[(k) * RP + rp + 4]);\
    const v2f f0 = {fa.x, fa.y}, f1 = {fa.z, fa.w};                          \
    const v2f f2 = {fb.x, fb.y}, f3 = {fb.z, fb.w};                          \
    _Pragma("unroll")                                                        \
    for (int j = 0; j < 4; j++) {                                            \
        const v2f ws = {W[j].comp, W[j].comp};                               \
        acc[j][0] += ws * f0; acc[j][1] += ws * f1;                          \
        acc[j][2] += ws * f2; acc[j][3] += ws * f3;                          \
    } } while (0)

#define FMA_STEP(W, k0) do {                                                 \
    FMA_K(W, x, (k0) + 0); FMA_K(W, y, (k0) + 1);                            \
    FMA_K(W, z, (k0) + 2); FMA_K(W, w, (k0) + 3); } while (0)

#define LD_W(W, kx) do { const int kb_ = (kx) * 4;                           \
    W[0] = *reinterpret_cast<const float4*>(wr0 + kb_);                      \
    W[1] = *reinterpret_cast<const float4*>(wr1 + kb_);                      \
    W[2] = *reinterpret_cast<const float4*>(wr2 + kb_);                      \
    W[3] = *reinterpret_cast<const float4*>(wr3 + kb_); } while (0)

template<int NF, int NOUT, bool SELECT>
__global__ __launch_bounds__(256, 4) void mlp_kernel(
    const float* __restrict__ fin,   // [B/32][NF][32] block-transposed
    const float* __restrict__ bn,    // [2*NF]
    const float* __restrict__ w1,    // [200][NF]
    const float* __restrict__ b1,    // [200]
    const float* __restrict__ w2,    // [NOUT][200]
    const float* __restrict__ b2,    // [NOUT]
    const float* __restrict__ vectors, // [B][10][4] (SELECT only)
    float* __restrict__ selout,      // [B][6][4]   (SELECT only)
    float* __restrict__ out,         // [B][21]
    int out_off)
{
    constexpr int RB = 32;
    constexpr int RP = 36;           // row stride (16B-aligned, conflict-free reads)
    __shared__ __align__(16) float U[FFDIM * RP];
    __shared__ float s_scale[NF], s_shift[NF];
    __shared__ float s_out[RB * 12];
    __shared__ int   s_idx[RB * 6];

    const int tid = threadIdx.x;
    const int blk = blockIdx.x;

    for (int k = tid; k < NF; k += 256) { s_scale[k] = bn[k]; s_shift[k] = bn[NF + k]; }
    __syncthreads();

    // Phase A: coalesced float4 read of transposed features, BN affine, LDS write.
    {
        const float4* fb4 = reinterpret_cast<const float4*>(fin + (size_t)blk * NF * 32);
        for (int q4 = tid; q4 < NF * 8; q4 += 256) {
            const int c = q4 >> 3, r4a = (q4 & 7) * 4;
            const float4 v = fb4[q4];
            const float sc = s_scale[c], sh = s_shift[c];
            float4 o;
            o.x = v.x * sc + sh; o.y = v.y * sc + sh;
            o.z = v.z * sc + sh; o.w = v.w * sc + sh;
            *reinterpret_cast<float4*>(&U[c * RP + r4a]) = o;
        }
    }
    __syncthreads();

    // Phase B: H = relu(W1 @ f + b1). Thread = 8 rows x 4 neurons.
    const int rp = (tid & 3) * 8;            // row position: 0/8/16/24
    const int nc = tid >> 2;                 // neuron column: 0..63
    const bool n3ok = (nc < FFDIM - 192);    // neuron 192+nc exists (8 of 64)

    const float* wr0 = w1 + (size_t)nc * NF;
    const float* wr1 = w1 + (size_t)(nc + 64) * NF;
    const float* wr2 = w1 + (size_t)(nc + 128) * NF;
    const float* wr3 = w1 + (size_t)(n3ok ? nc + 192 : nc) * NF;  // dummy if absent
    const float bb0 = b1[nc], bb1 = b1[nc + 64], bb2 = b1[nc + 128];
    const float bb3 = n3ok ? b1[nc + 192] : 0.f;

    v2f acc[4][4];
    #pragma unroll
    for (int j = 0; j < 4; j++)
        #pragma unroll
        for (int h = 0; h < 4; h++) acc[j][h] = (v2f){0.f, 0.f};

    constexpr int NF4 = NF / 4;
    float4 wA[4], wB[4];
    LD_W(wA, 0);
    int kc = 0;
    for (; kc + 2 <= NF4; kc += 2) {
        LD_W(wB, kc + 1);                            // prefetch odd slice
        __builtin_amdgcn_sched_barrier(0);           // pin: loads stay above
        FMA_STEP(wA, kc * 4);                        // 128-cyc FMA block
        LD_W(wA, (kc + 2 < NF4) ? (kc + 2) : (NF4 - 1));  // prefetch next even
        __builtin_amdgcn_sched_barrier(0);
        FMA_STEP(wB, (kc + 1) * 4);
    }
    if (kc < NF4) FMA_STEP(wA, kc * 4);              // odd-NF4 tail (NF=140)
    __syncthreads();                                 // all waves done reading U as FT

    // H-write: neuron n -> U[n*RP + rp..rp+7]
    {
        float4 ha, hb;
        #define HSTORE(J, N, BB) do {                                        \
            ha.x = acc[J][0][0] + (BB); ha.x = ha.x > 0.f ? ha.x : 0.f;      \
            ha.y = acc[J][0][1] + (BB); ha.y = ha.y > 0.f ? ha.y : 0.f;      \
            ha.z = acc[J][1][0] + (BB); ha.z = ha.z > 0.f ? ha.z : 0.f;      \
            ha.w = acc[J][1][1] + (BB); ha.w = ha.w > 0.f ? ha.w : 0.f;      \
            hb.x = acc[J][2][0] + (BB); hb.x = hb.x > 0.f ? hb.x : 0.f;      \
            hb.y = acc[J][2][1] + (BB); hb.y = hb.y > 0.f ? hb.y : 0.f;      \
            hb.z = acc[J][3][0] + (BB); hb.z = hb.z > 0.f ? hb.z : 0.f;      \
            hb.w = acc[J][3][1] + (BB); hb.w = hb.w > 0.f ? hb.w : 0.f;      \
            *reinterpret_cast<float4*>(&U[(N) * RP + rp]) = ha;              \
            *reinterpret_cast<float4*>(&U[(N) * RP + rp + 4]) = hb;          \
        } while (0)
        HSTORE(0, nc, bb0);
        HSTORE(1, nc + 64, bb1);
        HSTORE(2, nc + 128, bb2);
        if (n3ok) HSTORE(3, nc + 192, bb3);
        #undef HSTORE
    }
    __syncthreads();

    // Phase C: out[r][o] = b2[o] + sum_k h[r][k] * w2[o][k]  (packed pairs over k)
    {
        const int r = tid & 31, og = tid >> 5;
        for (int o = og; o < NOUT; o += 8) {
            v2f a2 = (v2f){b2[o], 0.f};
            const v2f* w2p = reinterpret_cast<const v2f*>(w2 + (size_t)o * FFDIM);
            for (int kp = 0; kp < FFDIM / 2; kp++) {
                const v2f hh = (v2f){U[(2 * kp) * RP + r], U[(2 * kp + 1) * RP + r]};
                a2 += w2p[kp] * hh;
            }
            s_out[r * 12 + o] = a2[0] + a2[1];
        }
    }
    __syncthreads();

    if (SELECT) {
        if (tid < RB) {              // per-row top-6 (ties -> lowest index), sorted asc
            float sc[10];
            #pragma unroll
            for (int o = 0; o < 10; o++) sc[o] = s_out[tid * 12 + o];
            bool used[10];
            #pragma unroll
            for (int o = 0; o < 10; o++) used[o] = false;
            int ids[6];
            for (int k = 0; k < 6; k++) {
                float m = -3.0e38f; int mi = 0;
                for (int o = 0; o < 10; o++)
                    if (!used[o] && sc[o] > m) { m = sc[o]; mi = o; }
                used[mi] = true; ids[k] = mi;
            }
            for (int a2i = 1; a2i < 6; a2i++) {  // insertion sort ascending
                const int v = ids[a2i]; int bp = a2i - 1;
                while (bp >= 0 && ids[bp] > v) { ids[bp + 1] = ids[bp]; bp--; }
                ids[bp + 1] = v;
            }
            #pragma unroll
            for (int k = 0; k < 6; k++) s_idx[tid * 6 + k] = ids[k];
        }
        __syncthreads();
        for (int q = tid; q < RB * 6; q += 256) {    // float4 gather of selected jets
            const int r2 = q / 6, j = q - r2 * 6;
            reinterpret_cast<float4*>(selout)[(size_t)blk * RB * 6 + q] =
                reinterpret_cast<const float4*>(vectors)
                    [(size_t)(blk * RB + r2) * NJ + s_idx[r2 * 6 + j]];
        }
    }

    for (int q = tid; q < RB * NOUT; q += 256) {
        const int r2 = q / NOUT, o = q - r2 * NOUT;
        out[(size_t)(blk * RB + r2) * OUTSTRIDE + out_off + o] = s_out[r2 * 12 + o];
    }
}

extern "C" void kernel_launch(void* const* d_in, const int* in_sizes, int n_in,
                              void* d_out, int out_size, void* d_ws, size_t ws_size,
                              hipStream_t stream) {
    const float* vectors  = (const float*)d_in[0];
    const float* isr_cola = (const float*)d_in[1];
    const float* isr_we   = (const float*)d_in[2];
    const float* isr_wd   = (const float*)d_in[3];
    const float* isr_bn_g = (const float*)d_in[4];
    const float* isr_bn_b = (const float*)d_in[5];
    const float* isr_w1   = (const float*)d_in[6];
    const float* isr_b1   = (const float*)d_in[7];
    const float* isr_w2   = (const float*)d_in[8];
    const float* isr_b2   = (const float*)d_in[9];
    const float* dec_cola = (const float*)d_in[10];
    const float* dec_we   = (const float*)d_in[11];
    const float* dec_wd   = (const float*)d_in[12];
    const float* dec_bn_g = (const float*)d_in[13];
    const float* dec_bn_b = (const float*)d_in[14];
    const float* dec_w1   = (const float*)d_in[15];
    const float* dec_b1   = (const float*)d_in[16];
    const float* dec_w2   = (const float*)d_in[17];
    const float* dec_b2   = (const float*)d_in[18];
    float* out = (float*)d_out;
    float* ws  = (float*)d_ws;

    // workspace layout (floats); f_buf reused by both heads (~29.4 MB total)
    float* f_buf  = ws;                    // 32768*160 = 5,242,880
    float* sel    = f_buf + 5242880;       // 32768*24 = 786,432
    float* ps     = sel + 786432;          // 160*4096 = 655,360
    float* pq     = ps + 655360;           // 655,360
    float* bn_i   = pq + 655360;           // 320
    float* bn_d   = bn_i + 320;            // 280

    feat_kernel<10, 32><<<4096, 256, 0, stream>>>(vectors, isr_cola, isr_we, isr_wd,
                                                  f_buf, ps, pq);
    bn_reduce<160><<<160, 256, 0, stream>>>(ps, pq, isr_bn_g, isr_bn_b, bn_i);
    mlp_kernel<160, 10, true><<<1024, 256, 0, stream>>>(f_buf, bn_i, isr_w1, isr_b1,
                                                        isr_w2, isr_b2, vectors, sel,
                                                        out, 0);
    feat_kernel<6, 28><<<4096, 256, 0, stream>>>(sel, dec_cola, dec_we, dec_wd,
                                                 f_buf, ps, pq);
    bn_reduce<140><<<140, 256, 0, stream>>>(ps, pq, dec_bn_g, dec_bn_b, bn_d);
    mlp_kernel<140, 11, false><<<1024, 256, 0, stream>>>(f_buf, bn_d, dec_w1, dec_b1,
                                                         dec_w2, dec_b2, nullptr, nullptr,
                                                         out, 10);
}

// Round 5
// 159.057 us; speedup vs baseline: 1.9363x; 1.0207x over previous
//
#include <hip/hip_runtime.h>

// Hydra_56633438765296: two-head LoLa/CoLa jet network, fp32 (no fp32 MFMA on CDNA4;
// rank-sensitive top-6 between heads keeps everything fp32 vector math).
// R4 post-mortem: FC1 was bottlenecked by per-thread scattered weight streaming from
// L2 (537 MB/dispatch, 640B-stride) with poor latency hiding at 16 waves/CU.
// R5: weights staged in LDS as double-buffered 4-k tiles (one barrier/tile,
// 2-deep global prefetch); FC1 = 4 rows x 7 neurons/thread, weight reads are
// conflict-free broadcast b128 from LDS -> loop is VALU-bound (56 pk-FMA vs
// ~11 LDS ops per tile).

#define BATCH 32768
#define NJ 10
#define FFDIM 200
#define OUTSTRIDE 21
#define NFEATBLK 4096

typedef float v2f __attribute__((ext_vector_type(2)));

// ---------------- features kernel: cola + lola + BN partials ----------------
template<int NIN, int NP>
__global__ __launch_bounds__(256) void feat_kernel(
    const float* __restrict__ vin,    // [B][NIN][4]
    const float* __restrict__ cola,   // [22][NIN]
    const float* __restrict__ we,     // [NP][NP]
    const float* __restrict__ wd,     // [NP][NP]
    float* __restrict__ fout,         // [B/32][F][32]
    float* __restrict__ psum,         // [F][4096]
    float* __restrict__ psq)          // [F][4096]
{
    constexpr int NC = 22;
    constexpr int F  = NP * 5;
    constexpr int RB = 8;             // rows per block
    constexpr int SW = NP + 1;        // odd stride -> conflict-free i-indexed reads
    constexpr int SF = F + 8;         // 2-way max on transposed readout
    __shared__ float s_cola[NC * NIN];
    __shared__ float s_we[NP * SW];
    __shared__ float s_wd[NP * SW];
    __shared__ float4 s_x[RB][NP];
    __shared__ float s_m2[RB][NP];
    __shared__ float s_f[RB * SF];

    const int tid = threadIdx.x;
    const int blk = blockIdx.x;

    for (int k = tid; k < NC * NIN; k += 256) s_cola[k] = cola[k];
    for (int k = tid; k < NP * NP; k += 256) {
        const int i2 = k / NP, j2 = k - i2 * NP;
        s_we[i2 * SW + j2] = we[k];
        s_wd[i2 * SW + j2] = wd[k];
    }
    for (int k = tid; k < RB * NIN * 4; k += 256)
        ((float*)&s_x[0][0])[(k / (NIN * 4)) * NP * 4 + (k % (NIN * 4))] =
            vin[(size_t)blk * RB * NIN * 4 + k];
    __syncthreads();

    const int r = tid >> 5;          // row in block (8)
    const int i = tid & 31;          // particle slot

    if (i >= NIN && i < NP) {        // learned combos
        const int c = i - NIN;
        float4 x = make_float4(0.f, 0.f, 0.f, 0.f);
        #pragma unroll
        for (int j = 0; j < NIN; j++) {
            const float w = s_cola[c * NIN + j];
            const float4 xj = s_x[r][j];
            x.x += w * xj.x; x.y += w * xj.y; x.z += w * xj.z; x.w += w * xj.w;
        }
        s_x[r][i] = x;
    }
    __syncthreads();

    float m2 = 0.f, pt = 0.f;
    float4 xi = make_float4(0.f, 0.f, 0.f, 0.f);
    if (i < NP) {
        xi = s_x[r][i];
        m2 = xi.x * xi.x - xi.y * xi.y - xi.z * xi.z - xi.w * xi.w;
        pt = sqrtf(xi.y * xi.y + xi.z * xi.z);
        s_m2[r][i] = m2;
    }
    __syncthreads();
    if (i < NP) {
        float wesum = 0.f, wdsum = 0.f;
        for (int j = 0; j < NP; j++) {
            const float4 xj = s_x[r][j];                    // broadcast b128
            wesum += s_we[i * SW + j] * xj.x;               // conflict-free
            const float g = xi.x * xj.x - xi.y * xj.y - xi.z * xj.z - xi.w * xj.w;
            wdsum += s_wd[i * SW + j] * (m2 + s_m2[r][j] - 2.0f * g);
        }
        s_f[r * SF + i * 5 + 0] = m2;
        s_f[r * SF + i * 5 + 1] = pt;
        s_f[r * SF + i * 5 + 2] = xi.x;
        s_f[r * SF + i * 5 + 3] = wesum;
        s_f[r * SF + i * 5 + 4] = wdsum;
    }
    __syncthreads();

    // block-transposed write: fout[blk>>2][c][(blk&3)*8 + rr]
    const size_t base = (size_t)(blk >> 2) * F * 32 + (blk & 3) * 8;
    for (int q = tid; q < F * RB; q += 256) {
        const int c = q >> 3, rr = q & 7;
        fout[base + (size_t)c * 32 + rr] = s_f[rr * SF + c];
    }

    if (tid < F) {                   // per-block BN partials (deterministic)
        float s = 0.f, s2 = 0.f;
        #pragma unroll
        for (int rr = 0; rr < RB; rr++) {
            const float v = s_f[rr * SF + tid];
            s += v; s2 += v * v;
        }
        psum[(size_t)tid * NFEATBLK + blk] = s;
        psq [(size_t)tid * NFEATBLK + blk] = s2;
    }
}

// ---------------- BN reduce: partials -> per-feature scale/shift ----------------
template<int F>
__global__ __launch_bounds__(256) void bn_reduce(
    const float* __restrict__ psum, const float* __restrict__ psq,
    const float* __restrict__ gamma, const float* __restrict__ beta,
    float* __restrict__ bn)          // [2*F]: scale then shift
{
    __shared__ float s1[256], s2[256];
    const int f = blockIdx.x, tid = threadIdx.x;
    float a = 0.f, b = 0.f;
    for (int bk = tid; bk < NFEATBLK; bk += 256) {
        a += psum[(size_t)f * NFEATBLK + bk];
        b += psq [(size_t)f * NFEATBLK + bk];
    }
    s1[tid] = a; s2[tid] = b; __syncthreads();
    for (int s = 128; s > 0; s >>= 1) {
        if (tid < s) { s1[tid] += s1[tid + s]; s2[tid] += s2[tid + s]; }
        __syncthreads();
    }
    if (tid == 0) {
        const float mu  = s1[0] / (float)BATCH;
        const float var = s2[0] / (float)BATCH - mu * mu;
        const float sc  = gamma[f] * rsqrtf(var + 1e-5f);
        bn[f]     = sc;
        bn[F + f] = beta[f] - mu * sc;
    }
}

// ---------------- MLP kernel: BN affine + FC1(relu) + FC2 (+ top-6 select) ----------------
// FC1: thread = 4 rows x 7 neurons; w1 staged in LDS as double-buffered
// [224][4] k-tiles; broadcast b128 reads, one barrier per tile, 2-deep prefetch.
template<int NF, int NOUT, bool SELECT>
__global__ __launch_bounds__(256, 4) void mlp_kernel(
    const float* __restrict__ fin,   // [B/32][NF][32] block-transposed
    const float* __restrict__ bn,    // [2*NF]
    const float* __restrict__ w1,    // [200][NF]
    const float* __restrict__ b1,    // [200]
    const float* __restrict__ w2,    // [NOUT][200]
    const float* __restrict__ b2,    // [NOUT]
    const float* __restrict__ vectors, // [B][10][4] (SELECT only)
    float* __restrict__ selout,      // [B][6][4]   (SELECT only)
    float* __restrict__ out,         // [B][21]
    int out_off)
{
    constexpr int RB = 32;
    constexpr int RP = 36;           // row stride (16B-aligned, conflict-free reads)
    constexpr int NF4 = NF / 4;
    __shared__ __align__(16) float U[FFDIM * RP];
    __shared__ __align__(16) float s_w[2][224 * 4];   // [buf][neuron][4 k's]
    __shared__ float s_scale[NF], s_shift[NF];
    __shared__ float s_out[RB * 12];
    __shared__ int   s_idx[RB * 6];

    const int tid = threadIdx.x;
    const int blk = blockIdx.x;

    for (int k = tid; k < NF; k += 256) { s_scale[k] = bn[k]; s_shift[k] = bn[NF + k]; }
    __syncthreads();

    // Phase A: coalesced float4 read of transposed features, BN affine, LDS write.
    {
        const float4* fb4 = reinterpret_cast<const float4*>(fin + (size_t)blk * NF * 32);
        for (int q4 = tid; q4 < NF * 8; q4 += 256) {
            const int c = q4 >> 3, r4a = (q4 & 7) * 4;
            const float4 v = fb4[q4];
            const float sc = s_scale[c], sh = s_shift[c];
            float4 o;
            o.x = v.x * sc + sh; o.y = v.y * sc + sh;
            o.z = v.z * sc + sh; o.w = v.w * sc + sh;
            *reinterpret_cast<float4*>(&U[c * RP + r4a]) = o;
        }
    }

    // Phase B: H = relu(W1 @ f + b1). Thread = 4 rows x 7 neurons.
    const int rp = (tid & 7) * 4;            // row position: 0,4,...,28
    const int nc = tid >> 3;                 // neuron column: 0..31
    const bool n6ok = (nc < FFDIM - 192);    // neuron 192+nc exists (nc<8)

    float bb[7];
    #pragma unroll
    for (int j = 0; j < 6; j++) bb[j] = b1[nc + 32 * j];
    bb[6] = n6ok ? b1[nc + 192] : 0.f;

    v2f acc[7][2];
    #pragma unroll
    for (int j = 0; j < 7; j++) { acc[j][0] = (v2f){0.f, 0.f}; acc[j][1] = (v2f){0.f, 0.f}; }

    // weight staging: tid<200 handles neuron row `tid`; tile kt = k's [4kt,4kt+4)
    const bool wld = (tid < FFDIM);
    float4 wv0, wv1;                          // 2-deep prefetch registers
    if (wld) {
        wv0 = *reinterpret_cast<const float4*>(w1 + (size_t)tid * NF);          // tile 0
        wv1 = *reinterpret_cast<const float4*>(w1 + (size_t)tid * NF + 4);      // tile 1
        *reinterpret_cast<float4*>(&s_w[0][tid * 4]) = wv0;                     // write tile 0
    }
    __syncthreads();     // U (features) + s_w[0] ready

    for (int kt = 0; kt < NF4; kt++) {
        const int b = kt & 1;
        // compute tile kt from s_w[b]: broadcast b128 weight reads (conflict-free)
        float4 wq[7];
        #pragma unroll
        for (int j = 0; j < 7; j++)
            wq[j] = *reinterpret_cast<const float4*>(&s_w[b][(nc + 32 * j) * 4]);
        #pragma unroll
        for (int kk = 0; kk < 4; kk++) {
            const float4 fa = *reinterpret_cast<const float4*>(&U[(kt * 4 + kk) * RP + rp]);
            const v2f flo = (v2f){fa.x, fa.y}, fhi = (v2f){fa.z, fa.w};
            #pragma unroll
            for (int j = 0; j < 7; j++) {
                const float w = kk == 0 ? wq[j].x : kk == 1 ? wq[j].y
                              : kk == 2 ? wq[j].z : wq[j].w;
                const v2f ws = (v2f){w, w};
                acc[j][0] += ws * flo;
                acc[j][1] += ws * fhi;
            }
        }
        // stage tile kt+1 into the other buffer; prefetch tile kt+2
        if (wld && kt + 1 < NF4) {
            *reinterpret_cast<float4*>(&s_w[b ^ 1][tid * 4]) = wv1;
            wv1 = wv0;   // shift not needed, but keep 2-deep: load kt+2
            const int knext = (kt + 2 < NF4) ? (kt + 2) * 4 : (NF4 - 1) * 4;
            wv1 = *reinterpret_cast<const float4*>(w1 + (size_t)tid * NF + knext);
        }
        __syncthreads();
    }

    // H-write: neuron n -> U[n*RP + rp .. rp+3]
    #pragma unroll
    for (int j = 0; j < 7; j++) {
        if (j < 6 || n6ok) {
            const int n = nc + 32 * j;
            float4 h;
            h.x = acc[j][0][0] + bb[j]; h.x = h.x > 0.f ? h.x : 0.f;
            h.y = acc[j][0][1] + bb[j]; h.y = h.y > 0.f ? h.y : 0.f;
            h.z = acc[j][1][0] + bb[j]; h.z = h.z > 0.f ? h.z : 0.f;
            h.w = acc[j][1][1] + bb[j]; h.w = h.w > 0.f ? h.w : 0.f;
            *reinterpret_cast<float4*>(&U[n * RP + rp]) = h;
        }
    }
    __syncthreads();

    // Phase C: out[r][o] = b2[o] + sum_k h[r][k] * w2[o][k]  (packed pairs over k)
    {
        const int r = tid & 31, og = tid >> 5;
        for (int o = og; o < NOUT; o += 8) {
            v2f a2 = (v2f){b2[o], 0.f};
            const v2f* w2p = reinterpret_cast<const v2f*>(w2 + (size_t)o * FFDIM);
            for (int kp = 0; kp < FFDIM / 2; kp++) {
                const v2f hh = (v2f){U[(2 * kp) * RP + r], U[(2 * kp + 1) * RP + r]};
                a2 += w2p[kp] * hh;
            }
            s_out[r * 12 + o] = a2[0] + a2[1];
        }
    }
    __syncthreads();

    if (SELECT) {
        if (tid < RB) {              // per-row top-6 (ties -> lowest index), sorted asc
            float sc[10];
            #pragma unroll
            for (int o = 0; o < 10; o++) sc[o] = s_out[tid * 12 + o];
            bool used[10];
            #pragma unroll
            for (int o = 0; o < 10; o++) used[o] = false;
            int ids[6];
            for (int k = 0; k < 6; k++) {
                float m = -3.0e38f; int mi = 0;
                for (int o = 0; o < 10; o++)
                    if (!used[o] && sc[o] > m) { m = sc[o]; mi = o; }
                used[mi] = true; ids[k] = mi;
            }
            for (int a2i = 1; a2i < 6; a2i++) {  // insertion sort ascending
                const int v = ids[a2i]; int bp = a2i - 1;
                while (bp >= 0 && ids[bp] > v) { ids[bp + 1] = ids[bp]; bp--; }
                ids[bp + 1] = v;
            }
            #pragma unroll
            for (int k = 0; k < 6; k++) s_idx[tid * 6 + k] = ids[k];
        }
        __syncthreads();
        for (int q = tid; q < RB * 6; q += 256) {    // float4 gather of selected jets
            const int r2 = q / 6, j = q - r2 * 6;
            reinterpret_cast<float4*>(selout)[(size_t)blk * RB * 6 + q] =
                reinterpret_cast<const float4*>(vectors)
                    [(size_t)(blk * RB + r2) * NJ + s_idx[r2 * 6 + j]];
        }
    }

    for (int q = tid; q < RB * NOUT; q += 256) {
        const int r2 = q / NOUT, o = q - r2 * NOUT;
        out[(size_t)(blk * RB + r2) * OUTSTRIDE + out_off + o] = s_out[r2 * 12 + o];
    }
}

extern "C" void kernel_launch(void* const* d_in, const int* in_sizes, int n_in,
                              void* d_out, int out_size, void* d_ws, size_t ws_size,
                              hipStream_t stream) {
    const float* vectors  = (const float*)d_in[0];
    const float* isr_cola = (const float*)d_in[1];
    const float* isr_we   = (const float*)d_in[2];
    const float* isr_wd   = (const float*)d_in[3];
    const float* isr_bn_g = (const float*)d_in[4];
    const float* isr_bn_b = (const float*)d_in[5];
    const float* isr_w1   = (const float*)d_in[6];
    const float* isr_b1   = (const float*)d_in[7];
    const float* isr_w2   = (const float*)d_in[8];
    const float* isr_b2   = (const float*)d_in[9];
    const float* dec_cola = (const float*)d_in[10];
    const float* dec_we   = (const float*)d_in[11];
    const float* dec_wd   = (const float*)d_in[12];
    const float* dec_bn_g = (const float*)d_in[13];
    const float* dec_bn_b = (const float*)d_in[14];
    const float* dec_w1   = (const float*)d_in[15];
    const float* dec_b1   = (const float*)d_in[16];
    const float* dec_w2   = (const float*)d_in[17];
    const float* dec_b2   = (const float*)d_in[18];
    float* out = (float*)d_out;
    float* ws  = (float*)d_ws;

    // workspace layout (floats); f_buf reused by both heads (~29.4 MB total)
    float* f_buf  = ws;                    // 32768*160 = 5,242,880
    float* sel    = f_buf + 5242880;       // 32768*24 = 786,432
    float* ps     = sel + 786432;          // 160*4096 = 655,360
    float* pq     = ps + 655360;           // 655,360
    float* bn_i   = pq + 655360;           // 320
    float* bn_d   = bn_i + 320;            // 280

    feat_kernel<10, 32><<<4096, 256, 0, stream>>>(vectors, isr_cola, isr_we, isr_wd,
                                                  f_buf, ps, pq);
    bn_reduce<160><<<160, 256, 0, stream>>>(ps, pq, isr_bn_g, isr_bn_b, bn_i);
    mlp_kernel<160, 10, true><<<1024, 256, 0, stream>>>(f_buf, bn_i, isr_w1, isr_b1,
                                                        isr_w2, isr_b2, vectors, sel,
                                                        out, 0);
    feat_kernel<6, 28><<<4096, 256, 0, stream>>>(sel, dec_cola, dec_we, dec_wd,
                                                 f_buf, ps, pq);
    bn_reduce<140><<<140, 256, 0, stream>>>(ps, pq, dec_bn_g, dec_bn_b, bn_d);
    mlp_kernel<140, 11, false><<<1024, 256, 0, stream>>>(f_buf, bn_d, dec_w1, dec_b1,
                                                         dec_w2, dec_b2, nullptr, nullptr,
                                                         out, 10);
}